// Round 3
// baseline (3715.435 us; speedup 1.0000x reference)
//
#include <hip/hip_runtime.h>

#define B_ 16
#define N_ 1024
#define M_ 4096
#define D_ 64
#define SROWS_ (N_ + 63)   // skewed row count per column tile: 1087
#define DECW_ (M_ / 16)    // dec u32 words per row (backtrack view)
#define BT_W 8             // backtrack window words per lane

__device__ __forceinline__ float finf() { return __builtin_inff(); }

// wave-wide shift right by 1 lane (lane l gets lane l-1's value; lane 0 gets old=0,
// always overwritten by a select). gfx9 DPP ctrl wave_shr:1 = 0x138.
__device__ __forceinline__ float wave_shr1(float x) {
  return __int_as_float(__builtin_amdgcn_update_dpp(
      0, __float_as_int(x), 0x138, 0xF, 0xF, false));
}

// ---------------------------------------------------------------------------
// prep: x2[b,i] = |x[b,i,:]|^2 ; copy x_t -> w_ts output
// ---------------------------------------------------------------------------
__global__ void prep_kernel(const float* __restrict__ x,
                            const float* __restrict__ x_t,
                            float* __restrict__ x2,
                            float* __restrict__ w_ts_out) {
  int id = blockIdx.x * blockDim.x + threadIdx.x;
  const float4* xr = (const float4*)(x + (size_t)id * D_);
  float s = 0.f;
#pragma unroll
  for (int e = 0; e < D_ / 4; ++e) {
    float4 v = xr[e];
    s += v.x * v.x + v.y * v.y + v.z * v.z + v.w * v.w;
  }
  x2[id] = s;
  w_ts_out[id] = x_t[id];
}

// ---------------------------------------------------------------------------
// GEMM: C[b,i,j] = x2 + y2 - 2*dot, written PRE-SKEWED per 256-col tile:
//   Cs[(b*NT + tile)*SROWS + (i + l)]*256 + ct   with l = ct>>2, ct = col in tile.
// So the DP wave's per-step read (fixed skewed row) is contiguous.
// ---------------------------------------------------------------------------
__global__ __launch_bounds__(256) void gemm_kernel(
    const float* __restrict__ x, const float* __restrict__ y,
    const float* __restrict__ x2, float* __restrict__ Cs,
    int chunkBase, int NT) {
  const int b = blockIdx.z;
  const int tile = blockIdx.x;             // tile within chunk
  const int lane = threadIdx.x & 63;
  const int wid = threadIdx.x >> 6;        // 64-col subgroup within tile
  const int ct = wid * 64 + lane;          // col within tile [0,256)
  const int j = chunkBase + tile * 256 + ct;
  const int l = ct >> 2;                   // owning DP lane
  float* CsT = Cs + (size_t)(b * NT + tile) * SROWS_ * 256;

  const float4* yrow = (const float4*)(y + ((size_t)b * M_ + j) * D_);
  float4 yr[D_ / 4];
#pragma unroll
  for (int e = 0; e < D_ / 4; ++e) yr[e] = yrow[e];
  float y2 = 0.f;
#pragma unroll
  for (int e = 0; e < D_ / 4; ++e)
    y2 += yr[e].x * yr[e].x + yr[e].y * yr[e].y + yr[e].z * yr[e].z + yr[e].w * yr[e].w;

  const int ibeg = blockIdx.y * 128;
  for (int i = ibeg; i < ibeg + 128; ++i) {
    const float4* xr = (const float4*)(x + ((size_t)b * N_ + i) * D_);
    float acc = 0.f;
#pragma unroll
    for (int e = 0; e < D_ / 4; ++e) {
      float4 xv = xr[e];
      acc += xv.x * yr[e].x + xv.y * yr[e].y + xv.z * yr[e].z + xv.w * yr[e].w;
    }
    CsT[(size_t)(i + l) * 256 + ct] = x2[b * N_ + i] + y2 - 2.f * acc;
  }
}

// ---------------------------------------------------------------------------
// Systolic DP over one 256*NT-column chunk, all 1024 rows. Wave W owns one
// 256-col tile; lane l owns cols [4l,4l+4) of it and at step s computes row
// i = s - l. Deps come from own regs (up), and lane l-1 via wave_shr1 DPP
// (left = its row i, diag = its row i-1). Lane 0 gets its edge from an LDS
// ring fed by wave W-1 (or the carry column of the previous chunk dispatch).
// Emits 2-bit decisions packed 4/byte; captures last-row min for cost/argmin.
// ---------------------------------------------------------------------------
template <int NT>
__global__ __launch_bounds__(NT * 64) void dtw_dp_systolic(
    const float* __restrict__ Cs, unsigned char* __restrict__ dec,
    const float* __restrict__ carryIn, float* __restrict__ carryOut,
    float* __restrict__ partV, int* __restrict__ partJ,
    int chunk, int nch, int hasCarry) {
  const int b = blockIdx.x;
  const int t = threadIdx.x;
  const int lane = t & 63;
  const int W = t >> 6;

  __shared__ float eRing[(NT - 1 > 0 ? NT - 1 : 1) * 64];
  __shared__ int eProg[(NT - 1 > 0 ? NT - 1 : 1)];
  __shared__ int eCons[NT];
  __shared__ float cring[256];
  __shared__ float redV[NT];
  __shared__ int redJ[NT];
  volatile float* vRing = eRing;
  volatile int* vProg = eProg;
  volatile int* vCons = eCons;

  if (t < NT - 1) vProg[t] = -1;
  if (t < NT) vCons[t] = 0;
  if (W == 0 && hasCarry) {  // preload carry rows [0,192)
    cring[lane] = carryIn[b * N_ + lane];
    cring[lane + 64] = carryIn[b * N_ + lane + 64];
    cring[lane + 128] = carryIn[b * N_ + lane + 128];
  }
  __syncthreads();

  const float INF = finf();
  float rv0 = INF, rv1 = INF, rvD = INF, rvN = INF;
  int progC = -1;
  if (W > 0) {
    while ((progC = vProg[W - 1]) < 1) {}
    rv0 = vRing[(W - 1) * 64 + 0];
    rv1 = vRing[(W - 1) * 64 + 1];
  } else if (hasCarry) {
    rv0 = cring[0];
    rv1 = cring[1];
  }

  const float* CsW = Cs + (size_t)(b * NT + W) * SROWS_ * 256;
  float4 cc[4];
#pragma unroll
  for (int p = 0; p < 4; ++p) cc[p] = ((const float4*)(CsW + (size_t)p * 256))[lane];

  float up0 = 0.f, up1 = 0.f, up2 = 0.f, up3 = 0.f;
  float dpp1 = INF, dpp2 = INF;
  float fin0 = INF, fin1 = INF, fin2 = INF, fin3 = INF;
  unsigned char* decB = dec + ((size_t)b << 20);
  const int colByte = chunk * NT * 64 + W * 64 + lane;
  const int jbase = (chunk * NT + W) * 256 + lane * 4;

#pragma unroll 4
  for (int s = 0; s < 1088; ++s) {
    const int i = s - lane;
    const float4 c4 = cc[s & 3];
    const bool row0 = (i == 0);
    const float left = (lane == 0) ? rv0 : dpp1;
    const float diag = (lane == 0) ? rvD : dpp2;

    float m0 = fminf(up0, left);
    float bv0 = fminf(diag, m0); bv0 = row0 ? 0.f : bv0;
    const float D0 = c4.x + bv0;
    unsigned int pk = (diag <= m0) ? 0u : ((up0 <= left) ? 1u : 2u);

    float m1 = fminf(up1, D0);
    float bv1 = fminf(up0, m1); bv1 = row0 ? 0.f : bv1;
    const float D1 = c4.y + bv1;
    pk |= ((up0 <= m1) ? 0u : ((up1 <= D0) ? 1u : 2u)) << 2;

    float m2 = fminf(up2, D1);
    float bv2 = fminf(up1, m2); bv2 = row0 ? 0.f : bv2;
    const float D2 = c4.z + bv2;
    pk |= ((up1 <= m2) ? 0u : ((up2 <= D1) ? 1u : 2u)) << 4;

    float m3 = fminf(up3, D2);
    float bv3 = fminf(up2, m3); bv3 = row0 ? 0.f : bv3;
    const float D3 = c4.w + bv3;
    pk |= ((up2 <= m3) ? 0u : ((up3 <= D2) ? 1u : 2u)) << 6;

    if ((unsigned)(i - 1) < (unsigned)(N_ - 1))
      decB[(size_t)i * 1024 + colByte] = (unsigned char)pk;
    if (i == N_ - 1) { fin0 = D0; fin1 = D1; fin2 = D2; fin3 = D3; }
    if (W == NT - 1 && lane == 63 && (unsigned)i < (unsigned)N_)
      carryOut[b * N_ + i] = D3;

    const float sh = wave_shr1(D3);
    dpp2 = dpp1; dpp1 = sh;
    up0 = D0; up1 = D1; up2 = D2; up3 = D3;

    if (W < NT - 1) {  // publish right edge for wave W+1
      const int rp = s - 63;
      if (lane == 63 && rp >= 0 && rp < N_) {
        if ((rp & 7) == 7) {
          int cv;
          while ((cv = vCons[W + 1]) < rp - 48) {}  // ring back-pressure
        }
        vRing[W * 64 + (rp & 63)] = D3;
        __builtin_amdgcn_s_waitcnt(0xC07F);  // lgkmcnt(0): ring before prog
        if ((rp & 7) == 7) vProg[W] = rp;
      }
    }
    if (W > 0 && lane == 0 && (s & 7) == 0) vCons[W] = s;

    // refills: C prefetch 4 ahead; edge value 2 ahead
    const int srow = s + 4;
    if (srow < SROWS_) cc[s & 3] = ((const float4*)(CsW + (size_t)srow * 256))[lane];
    const int need = s + 2;
    if (W > 0) {
      if (need <= N_ - 1) {
        while (progC < need) progC = vProg[W - 1];
        rvN = vRing[(W - 1) * 64 + (need & 63)];
      }
    } else if (hasCarry) {
      if (need <= N_ - 1) rvN = cring[need & 255];
      if ((s & 63) == 0 && s >= 64) {
        const int r = s + 128 + lane;
        if (r < N_) cring[r & 255] = carryIn[b * N_ + r];
      }
    }
    rvD = rv0; rv0 = rv1; rv1 = rvN;
  }

  // last-row (min, first-argmin) partial for this chunk
  float mv = fin0; int mj = jbase;
  if (fin1 < mv) { mv = fin1; mj = jbase + 1; }
  if (fin2 < mv) { mv = fin2; mj = jbase + 2; }
  if (fin3 < mv) { mv = fin3; mj = jbase + 3; }
#pragma unroll
  for (int off = 32; off > 0; off >>= 1) {
    const float ov = __shfl_down(mv, off);
    const int oj = __shfl_down(mj, off);
    if (ov < mv || (ov == mv && oj < mj)) { mv = ov; mj = oj; }
  }
  if (lane == 0) { redV[W] = mv; redJ[W] = mj; }
  __syncthreads();
  if (t == 0) {
#pragma unroll
    for (int w = 1; w < NT; ++w)
      if (redV[w] < mv) { mv = redV[w]; mj = redJ[w]; }
    partV[b * nch + chunk] = mv;
    partJ[b * nch + chunk] = mj;
  }
}

// ---------------------------------------------------------------------------
// Backtrack (round-2 validated): one wave/batch; lane l preloads an 8-word
// window of row i-l into LDS; lane 0 walks up to 64 rows in LDS; parallel
// y_t gather. Head: combine per-chunk (min, argmin) partials -> cost + j0.
// ---------------------------------------------------------------------------
__global__ __launch_bounds__(64) void backtrack_kernel(
    const unsigned int* __restrict__ dec, const float* __restrict__ partV,
    const int* __restrict__ partJ, int nch, const float* __restrict__ y_t,
    float* __restrict__ w_vs, float* __restrict__ cost_out) {
  const int b = blockIdx.x;
  const int lane = threadIdx.x;
  __shared__ unsigned int win[64][BT_W];
  __shared__ int st_i, st_j;
  __shared__ int jrow[65];
  const unsigned int* db = dec + (size_t)b * N_ * DECW_;
  const float* yt = y_t + b * M_;
  float* wv = w_vs + b * N_;

  if (lane == 0) {
    float bc = finf(); int bj = 0;
    for (int c = 0; c < nch; ++c) {  // chunks ascend in j: strict < keeps first
      const float v = partV[b * nch + c];
      const int j = partJ[b * nch + c];
      if (v < bc) { bc = v; bj = j; }
    }
    cost_out[b] = bc;
    st_i = N_ - 1;
    st_j = bj;
    wv[N_ - 1] = yt[bj];
  }
  for (;;) {
    __syncthreads();
    const int i = st_i, j = st_j;
    if (i <= 0) break;
    const int jw = j >> 4;
    int wb = jw - (BT_W - 1);
    if (wb < 0) wb = 0;
    const int r = i - lane;
    if (r >= 1) {
      const unsigned int* dr = db + (size_t)r * DECW_;
#pragma unroll
      for (int k = 0; k < BT_W; ++k) win[lane][k] = dr[wb + k];
    }
    __syncthreads();
    if (lane == 0) {
      const int base = wb << 4;
      int rr = i, cj = j;
      while (rr >= 1 && (i - rr) < 64) {
        const int l = i - rr;
        bool stuck = false;
        for (;;) {
          if (cj < base) { stuck = true; break; }
          const unsigned int wd = win[l][(cj >> 4) - wb];
          const int code = (int)((wd >> (2 * (cj & 15))) & 3u);
          if (code == 2) { --cj; continue; }
          if (code == 0) --cj;
          break;
        }
        if (stuck) break;
        --rr;
        jrow[i - rr] = cj;
      }
      st_i = rr;
      st_j = cj;
    }
    __syncthreads();
    const int ni = st_i;
    const int cnt = i - ni;
    if (lane < cnt) wv[i - 1 - lane] = yt[jrow[lane + 1]];
  }
}

// ---------------------------------------------------------------------------
extern "C" void kernel_launch(void* const* d_in, const int* in_sizes, int n_in,
                              void* d_out, int out_size, void* d_ws, size_t ws_size,
                              hipStream_t stream) {
  const float* x = (const float*)d_in[0];
  const float* y = (const float*)d_in[1];
  const float* x_t = (const float*)d_in[2];
  const float* y_t = (const float*)d_in[3];

  float* out_cost = (float*)d_out;      // [B_]
  float* out_wts = out_cost + B_;       // [B_][N_]
  float* out_wvs = out_wts + B_ * N_;   // [B_][N_]

  const size_t decBytes = (size_t)B_ * N_ * 1024;          // 16.78 MB
  const size_t x2Bytes = (size_t)B_ * N_ * 4;
  const size_t carryBytes = (size_t)B_ * N_ * 4;
  const size_t partBytes = (size_t)B_ * 8 * 4;
  const size_t cs4 = (size_t)B_ * 4 * SROWS_ * 256 * 4;    // 71.2 MB
  const size_t need4 = cs4 + decBytes + x2Bytes + 2 * carryBytes + 2 * partBytes;

  const int NT = (ws_size >= need4) ? 4 : 2;
  const int NCH = 16 / NT;  // 4096 / (NT*256)
  const size_t csBytes = (size_t)B_ * NT * SROWS_ * 256 * 4;

  char* ws = (char*)d_ws;
  float* Cs = (float*)ws;
  unsigned char* dec = (unsigned char*)(ws + csBytes);
  float* x2 = (float*)(ws + csBytes + decBytes);
  float* carryA = (float*)(ws + csBytes + decBytes + x2Bytes);
  float* carryB = carryA + B_ * N_;
  float* partV = carryB + B_ * N_;
  int* partJ = (int*)(partV + B_ * 8);

  prep_kernel<<<dim3((B_ * N_) / 256), 256, 0, stream>>>(x, x_t, x2, out_wts);

  float* cbuf[2] = {carryA, carryB};
  for (int c = 0; c < NCH; ++c) {
    const int chunkBase = c * NT * 256;
    gemm_kernel<<<dim3(NT, N_ / 128, B_), 256, 0, stream>>>(x, y, x2, Cs,
                                                            chunkBase, NT);
    const float* cin = cbuf[(c + 1) & 1];
    float* cout = cbuf[c & 1];
    if (NT == 4) {
      dtw_dp_systolic<4><<<dim3(B_), 256, 0, stream>>>(
          Cs, dec, cin, cout, partV, partJ, c, NCH, c > 0 ? 1 : 0);
    } else {
      dtw_dp_systolic<2><<<dim3(B_), 128, 0, stream>>>(
          Cs, dec, cin, cout, partV, partJ, c, NCH, c > 0 ? 1 : 0);
    }
  }

  backtrack_kernel<<<dim3(B_), 64, 0, stream>>>((const unsigned int*)dec, partV,
                                                partJ, NCH, y_t, out_wvs,
                                                out_cost);
}

// Round 4
// 2643.470 us; speedup vs baseline: 1.4055x; 1.4055x over previous
//
#include <hip/hip_runtime.h>

#define B_ 16
#define N_ 1024
#define M_ 4096
#define D_ 64
#define SROWS_ (N_ + 63)   // skewed rows per 256-col tile: 1087
#define BTQ_ 96            // backtrack window quads (384 cells)

__device__ __forceinline__ float finf() { return __builtin_inff(); }

// wave-wide shift right by 1 lane; lane 0 gets old (0), always select-overridden.
__device__ __forceinline__ float wave_shr1(float x) {
  return __int_as_float(__builtin_amdgcn_update_dpp(
      0, __float_as_int(x), 0x138, 0xF, 0xF, false));
}

// ---------------------------------------------------------------------------
__global__ void prep_kernel(const float* __restrict__ x,
                            const float* __restrict__ x_t,
                            float* __restrict__ x2,
                            float* __restrict__ w_ts_out) {
  int id = blockIdx.x * blockDim.x + threadIdx.x;
  const float4* xr = (const float4*)(x + (size_t)id * D_);
  float s = 0.f;
#pragma unroll
  for (int e = 0; e < D_ / 4; ++e) {
    float4 v = xr[e];
    s += v.x * v.x + v.y * v.y + v.z * v.z + v.w * v.w;
  }
  x2[id] = s;
  w_ts_out[id] = x_t[id];
}

// ---------------------------------------------------------------------------
// GEMM writing C pre-skewed per 256-col tile: Cs[tile][(i+l)*256 + ct], l=ct>>2.
// ---------------------------------------------------------------------------
__global__ __launch_bounds__(256) void gemm_kernel(
    const float* __restrict__ x, const float* __restrict__ y,
    const float* __restrict__ x2, float* __restrict__ Cs,
    int chunkBase, int NT) {
  const int b = blockIdx.z;
  const int tile = blockIdx.x;
  const int lane = threadIdx.x & 63;
  const int wid = threadIdx.x >> 6;
  const int ct = wid * 64 + lane;
  const int j = chunkBase + tile * 256 + ct;
  const int l = ct >> 2;
  float* CsT = Cs + (size_t)(b * NT + tile) * SROWS_ * 256;

  const float4* yrow = (const float4*)(y + ((size_t)b * M_ + j) * D_);
  float4 yr[D_ / 4];
#pragma unroll
  for (int e = 0; e < D_ / 4; ++e) yr[e] = yrow[e];
  float y2 = 0.f;
#pragma unroll
  for (int e = 0; e < D_ / 4; ++e)
    y2 += yr[e].x * yr[e].x + yr[e].y * yr[e].y + yr[e].z * yr[e].z + yr[e].w * yr[e].w;

  const int ibeg = blockIdx.y * 128;
  for (int i = ibeg; i < ibeg + 128; ++i) {
    const float4* xr = (const float4*)(x + ((size_t)b * N_ + i) * D_);
    float acc = 0.f;
#pragma unroll
    for (int e = 0; e < D_ / 4; ++e) {
      float4 xv = xr[e];
      acc += xv.x * yr[e].x + xv.y * yr[e].y + xv.z * yr[e].z + xv.w * yr[e].w;
    }
    CsT[(size_t)(i + l) * 256 + ct] = x2[b * N_ + i] + y2 - 2.f * acc;
  }
}

// ---------------------------------------------------------------------------
// Systolic DP. Wave W owns a 256-col tile; lane l owns 4 cols; step s => row
// i = s - lane. Edge handoff via LDS ring, polled/flagged once per 8 steps.
// dec written SKEWED: dec[(b*16+tileG)*SROWS + s]*64 + lane (contiguous/step).
// ---------------------------------------------------------------------------
template <int NT>
__global__ __launch_bounds__(NT * 64) void dtw_dp_systolic(
    const float* __restrict__ Cs, unsigned char* __restrict__ dec,
    const float* __restrict__ carryIn, float* __restrict__ carryOut,
    float* __restrict__ partV, int* __restrict__ partJ,
    int chunk, int nch, int hasCarry) {
  const int b = blockIdx.x;
  const int t = threadIdx.x;
  const int lane = t & 63;
  const int W = t >> 6;

  __shared__ float eRing[(NT > 1 ? NT - 1 : 1) * 64];
  __shared__ int eProg[(NT > 1 ? NT - 1 : 1)];
  __shared__ int eCons[NT + 1];
  __shared__ float cring[256];
  __shared__ float redV[NT];
  __shared__ int redJ[NT];
  volatile int* vProg = eProg;
  volatile int* vCons = eCons;

  if (t < (NT > 1 ? NT - 1 : 1)) vProg[t] = -1;
  if (t < NT + 1) vCons[t] = 0;
  if (W == 0 && hasCarry) {
    cring[lane] = carryIn[b * N_ + lane];
    cring[lane + 64] = carryIn[b * N_ + lane + 64];
    cring[lane + 128] = carryIn[b * N_ + lane + 128];
  }
  __syncthreads();

  const float INF = finf();
  const float* CsW = Cs + (size_t)(b * NT + W) * SROWS_ * 256;
  float4 cc[8];
#pragma unroll
  for (int p = 0; p < 8; ++p) cc[p] = ((const float4*)(CsW + (size_t)p * 256))[lane];

  float up0 = 0.f, up1 = 0.f, up2 = 0.f, up3 = 0.f;
  float dpp1 = INF, dpp2 = INF, lrPrev = INF;
  float fin0 = INF, fin1 = INF, fin2 = INF, fin3 = INF;
  const int tileG = chunk * NT + W;
  unsigned char* decL = dec + (size_t)(b * 16 + tileG) * SROWS_ * 64 + lane;
  const int jbase = tileG * 256 + lane * 4;

  for (int sb = 0; sb < 1088; sb += 8) {
    if (NT > 1 && W > 0) {
      if (sb < N_) {
        if (lane == 0) vCons[W] = sb;
        const int tgt = (sb + 7 < N_) ? (sb + 7) : (N_ - 1);
        while (vProg[W - 1] < tgt) {}
        asm volatile("" ::: "memory");
      }
    } else if (W == 0 && hasCarry) {
      if ((sb & 63) == 0 && sb >= 64) {
        const int r = sb + 128 + lane;
        if (r < N_) cring[r & 255] = carryIn[b * N_ + r];
      }
    }
#pragma unroll
    for (int k = 0; k < 8; ++k) {
      const int s = sb + k;
      const int i = s - lane;
      const float4 c4 = cc[k];
      float lval;
      if (NT > 1 && W > 0) lval = eRing[(W - 1) * 64 + (s & 63)];
      else if (hasCarry) lval = cring[s & 255];
      else lval = INF;
      const bool row0 = (i == 0);
      const float left = (lane == 0) ? lval : dpp1;
      const float diag = (lane == 0) ? lrPrev : dpp2;
      lrPrev = lval;

      float m0 = fminf(up0, left);
      float bv0 = fminf(diag, m0); bv0 = row0 ? 0.f : bv0;
      const float D0 = c4.x + bv0;
      unsigned int pk = (diag <= m0) ? 0u : ((up0 <= left) ? 1u : 2u);

      float m1 = fminf(up1, D0);
      float bv1 = fminf(up0, m1); bv1 = row0 ? 0.f : bv1;
      const float D1 = c4.y + bv1;
      pk |= ((up0 <= m1) ? 0u : ((up1 <= D0) ? 1u : 2u)) << 2;

      float m2 = fminf(up2, D1);
      float bv2 = fminf(up1, m2); bv2 = row0 ? 0.f : bv2;
      const float D2 = c4.z + bv2;
      pk |= ((up1 <= m2) ? 0u : ((up2 <= D1) ? 1u : 2u)) << 4;

      float m3 = fminf(up3, D2);
      float bv3 = fminf(up2, m3); bv3 = row0 ? 0.f : bv3;
      const float D3 = c4.w + bv3;
      pk |= ((up2 <= m3) ? 0u : ((up3 <= D2) ? 1u : 2u)) << 6;

      if ((unsigned)(i - 1) < (unsigned)(N_ - 1))
        decL[(size_t)s * 64] = (unsigned char)pk;
      if (i == N_ - 1) { fin0 = D0; fin1 = D1; fin2 = D2; fin3 = D3; }
      if (W == NT - 1 && lane == 63 && (unsigned)i < (unsigned)N_)
        carryOut[b * N_ + i] = D3;

      const float sh = wave_shr1(D3);
      dpp2 = dpp1; dpp1 = sh;
      up0 = D0; up1 = D1; up2 = D2; up3 = D3;

      if (NT > 1 && W < NT - 1) {
        const int rp = s - 63;
        if (lane == 63 && (unsigned)rp < (unsigned)N_) {
          eRing[W * 64 + (rp & 63)] = D3;
          if ((rp & 7) == 7) {
            asm volatile("" ::: "memory");
            __builtin_amdgcn_s_waitcnt(0xC07F);  // lgkmcnt(0)
            vProg[W] = rp;
            while (vCons[W + 1] < rp - 55) {}    // ring back-pressure
          }
        }
      }
      const int srow = s + 8;
      if (srow < SROWS_) cc[k] = ((const float4*)(CsW + (size_t)srow * 256))[lane];
    }
  }

  float mv = fin0; int mj = jbase;
  if (fin1 < mv) { mv = fin1; mj = jbase + 1; }
  if (fin2 < mv) { mv = fin2; mj = jbase + 2; }
  if (fin3 < mv) { mv = fin3; mj = jbase + 3; }
#pragma unroll
  for (int off = 32; off > 0; off >>= 1) {
    const float ov = __shfl_down(mv, off);
    const int oj = __shfl_down(mj, off);
    if (ov < mv || (ov == mv && oj < mj)) { mv = ov; mj = oj; }
  }
  if (lane == 0) { redV[W] = mv; redJ[W] = mj; }
  __syncthreads();
  if (t == 0) {
#pragma unroll
    for (int w = 1; w < NT; ++w)
      if (redV[w] < mv) { mv = redV[w]; mj = redJ[w]; }
    partV[b * nch + chunk] = mv;
    partJ[b * nch + chunk] = mj;
  }
}

// ---------------------------------------------------------------------------
// Backtrack over skewed dec. Per super-step: lane l loads a 96-quad window of
// row i-l; decodes a run-of-2 exit table (tab[c] = stop cell + its code) so
// the serial walk costs ~1 LDS read per row; parallel y_t gather at the end.
// ---------------------------------------------------------------------------
__global__ __launch_bounds__(64) void backtrack_kernel(
    const unsigned char* __restrict__ dec, const float* __restrict__ partV,
    const int* __restrict__ partJ, int nch, const float* __restrict__ y_t,
    float* __restrict__ w_vs, float* __restrict__ cost_out) {
  const int b = blockIdx.x;
  const int lane = threadIdx.x;
  __shared__ unsigned char win[64][BTQ_ + 4];
  __shared__ unsigned short tab[64][BTQ_ * 4 + 2];
  __shared__ int st_i, st_j;
  __shared__ int jrow[65];
  const size_t TS = (size_t)SROWS_ * 64;
  const unsigned char* db = dec + (size_t)b * 16 * TS;
  const float* yt = y_t + b * M_;
  float* wv = w_vs + b * N_;

  if (lane == 0) {
    float bc = finf(); int bj = 0;
    for (int c = 0; c < nch; ++c) {
      const float v = partV[b * nch + c];
      const int j = partJ[b * nch + c];
      if (v < bc) { bc = v; bj = j; }
    }
    cost_out[b] = bc;
    st_i = N_ - 1;
    st_j = bj;
    wv[N_ - 1] = yt[bj];
  }
  for (;;) {
    __syncthreads();
    const int i = st_i, j = st_j;
    if (i <= 0) break;
    const int qj = j >> 2;
    int qlo = qj - (BTQ_ - 1);
    if (qlo < 0) qlo = 0;
    const int r = i - lane;
    if (r >= 1) {
      for (int k = 0; k < BTQ_; ++k) {
        const int q = qlo + k;
        win[lane][k] = db[(size_t)(q >> 6) * TS + (size_t)(r + (q & 63)) * 64 + (q & 63)];
      }
      unsigned short run = 0xFFFF;  // stuck sentinel (run extends past window)
      for (int k = 0; k < BTQ_; ++k) {
        const unsigned int byte = win[lane][k];
#pragma unroll
        for (int cs = 0; cs < 4; ++cs) {
          const unsigned int code = (byte >> (2 * cs)) & 3u;
          const int c = 4 * k + cs;
          const unsigned short v =
              (code != 2u) ? (unsigned short)((c << 2) | code) : run;
          tab[lane][c] = v;
          run = v;
        }
      }
    }
    __syncthreads();
    if (lane == 0) {
      const int base = qlo << 2;
      int rr = i, cj = j;
      while (rr >= 1 && (i - rr) < 64) {
        const int l = i - rr;
        const int c = cj - base;
        if (c < 0) break;  // window exhausted; restart super-step
        const unsigned short v = tab[l][c];
        if (v == 0xFFFF) { cj = base - 1; break; }  // 2-run exits window
        const int e = v >> 2;
        const int ce = v & 3;
        cj = base + e - (ce == 0 ? 1 : 0);
        --rr;
        jrow[i - rr] = cj;
      }
      st_i = rr;
      st_j = cj;
    }
    __syncthreads();
    const int cnt = i - st_i;
    if (lane < cnt) wv[i - 1 - lane] = yt[jrow[lane + 1]];
  }
}

// ---------------------------------------------------------------------------
extern "C" void kernel_launch(void* const* d_in, const int* in_sizes, int n_in,
                              void* d_out, int out_size, void* d_ws, size_t ws_size,
                              hipStream_t stream) {
  const float* x = (const float*)d_in[0];
  const float* y = (const float*)d_in[1];
  const float* x_t = (const float*)d_in[2];
  const float* y_t = (const float*)d_in[3];

  float* out_cost = (float*)d_out;      // [B_]
  float* out_wts = out_cost + B_;       // [B_][N_]
  float* out_wvs = out_wts + B_ * N_;   // [B_][N_]

  const size_t decBytes = (size_t)B_ * 16 * SROWS_ * 64;   // 17.8 MB (skewed)
  const size_t x2Bytes = (size_t)B_ * N_ * 4;
  const size_t carryBytes = (size_t)B_ * N_ * 4;
  const size_t partBytes = (size_t)B_ * 8 * 4;
  const size_t cs4 = (size_t)B_ * 4 * SROWS_ * 256 * 4;    // 71.2 MB
  const size_t need4 = cs4 + decBytes + x2Bytes + 2 * carryBytes + 2 * partBytes;

  const int NT = (ws_size >= need4) ? 4 : 2;
  const int NCH = 16 / NT;
  const size_t csBytes = (size_t)B_ * NT * SROWS_ * 256 * 4;

  char* ws = (char*)d_ws;
  float* Cs = (float*)ws;
  unsigned char* dec = (unsigned char*)(ws + csBytes);
  float* x2 = (float*)(ws + csBytes + decBytes);
  float* carryA = (float*)(ws + csBytes + decBytes + x2Bytes);
  float* carryB = carryA + B_ * N_;
  float* partV = carryB + B_ * N_;
  int* partJ = (int*)(partV + B_ * 8);

  prep_kernel<<<dim3((B_ * N_) / 256), 256, 0, stream>>>(x, x_t, x2, out_wts);

  float* cbuf[2] = {carryA, carryB};
  for (int c = 0; c < NCH; ++c) {
    const int chunkBase = c * NT * 256;
    gemm_kernel<<<dim3(NT, N_ / 128, B_), 256, 0, stream>>>(x, y, x2, Cs,
                                                            chunkBase, NT);
    const float* cin = cbuf[(c + 1) & 1];
    float* cout = cbuf[c & 1];
    if (NT == 4) {
      dtw_dp_systolic<4><<<dim3(B_), 256, 0, stream>>>(
          Cs, dec, cin, cout, partV, partJ, c, NCH, c > 0 ? 1 : 0);
    } else {
      dtw_dp_systolic<2><<<dim3(B_), 128, 0, stream>>>(
          Cs, dec, cin, cout, partV, partJ, c, NCH, c > 0 ? 1 : 0);
    }
  }

  backtrack_kernel<<<dim3(B_), 64, 0, stream>>>(dec, partV, partJ, NCH, y_t,
                                                out_wvs, out_cost);
}

// Round 5
// 2336.026 us; speedup vs baseline: 1.5905x; 1.1316x over previous
//
#include <hip/hip_runtime.h>

#define B_ 16
#define N_ 1024
#define M_ 4096
#define D_ 64
#define SROWS_ (N_ + 63)   // skewed rows per 256-col tile: 1087
#define BTQ_ 96            // backtrack window quads (384 cells)

__device__ __forceinline__ float finf() { return __builtin_inff(); }

// wave-wide shift right by 1 lane; lane 0 gets old (0), always select-overridden.
__device__ __forceinline__ float wave_shr1(float x) {
  return __int_as_float(__builtin_amdgcn_update_dpp(
      0, __float_as_int(x), 0x138, 0xF, 0xF, false));
}

// ---------------------------------------------------------------------------
__global__ void prep_kernel(const float* __restrict__ x,
                            const float* __restrict__ x_t,
                            float* __restrict__ x2,
                            float* __restrict__ w_ts_out) {
  int id = blockIdx.x * blockDim.x + threadIdx.x;
  const float4* xr = (const float4*)(x + (size_t)id * D_);
  float s = 0.f;
#pragma unroll
  for (int e = 0; e < D_ / 4; ++e) {
    float4 v = xr[e];
    s += v.x * v.x + v.y * v.y + v.z * v.z + v.w * v.w;
  }
  x2[id] = s;
  w_ts_out[id] = x_t[id];
}

// ---------------------------------------------------------------------------
// GEMM writing C pre-skewed per 256-col tile: Cs[tile][(i+l)*256 + ct], l=ct>>2.
// ---------------------------------------------------------------------------
__global__ __launch_bounds__(256) void gemm_kernel(
    const float* __restrict__ x, const float* __restrict__ y,
    const float* __restrict__ x2, float* __restrict__ Cs,
    int chunkBase, int NT) {
  const int b = blockIdx.z;
  const int tile = blockIdx.x;
  const int lane = threadIdx.x & 63;
  const int wid = threadIdx.x >> 6;
  const int ct = wid * 64 + lane;
  const int j = chunkBase + tile * 256 + ct;
  const int l = ct >> 2;
  float* CsT = Cs + (size_t)(b * NT + tile) * SROWS_ * 256;

  const float4* yrow = (const float4*)(y + ((size_t)b * M_ + j) * D_);
  float4 yr[D_ / 4];
#pragma unroll
  for (int e = 0; e < D_ / 4; ++e) yr[e] = yrow[e];
  float y2 = 0.f;
#pragma unroll
  for (int e = 0; e < D_ / 4; ++e)
    y2 += yr[e].x * yr[e].x + yr[e].y * yr[e].y + yr[e].z * yr[e].z + yr[e].w * yr[e].w;

  const int ibeg = blockIdx.y * 128;
  for (int i = ibeg; i < ibeg + 128; ++i) {
    const float4* xr = (const float4*)(x + ((size_t)b * N_ + i) * D_);
    float acc = 0.f;
#pragma unroll
    for (int e = 0; e < D_ / 4; ++e) {
      float4 xv = xr[e];
      acc += xv.x * yr[e].x + xv.y * yr[e].y + xv.z * yr[e].z + xv.w * yr[e].w;
    }
    CsT[(size_t)(i + l) * 256 + ct] = x2[b * N_ + i] + y2 - 2.f * acc;
  }
}

// ---------------------------------------------------------------------------
// Systolic DP. Wave W owns a 256-col tile; lane l owns 4 cols; step s => row
// i = s - lane. Edge handoff via LDS ring, polled/flagged once per 8 steps.
// dec written SKEWED: byte [tile][s][lane] (contiguous 64B per wave-step).
// 8-step body fully hand-unrolled with NAMED float4 prefetch registers so the
// compiler cannot demote the ring to scratch or sink the refill loads
// (round-4: VGPR=44 + ~1017cyc/step indicated prefetch depth collapsed to ~1).
// ---------------------------------------------------------------------------
template <int NT>
__global__ __launch_bounds__(NT * 64) void dtw_dp_systolic(
    const float* __restrict__ Cs, unsigned char* __restrict__ dec,
    const float* __restrict__ carryIn, float* __restrict__ carryOut,
    float* __restrict__ partV, int* __restrict__ partJ,
    int chunk, int nch, int hasCarry) {
  const int b = blockIdx.x;
  const int t = threadIdx.x;
  const int lane = t & 63;
  const int W = t >> 6;

  __shared__ float eRing[(NT > 1 ? NT - 1 : 1) * 64];
  __shared__ int eProg[(NT > 1 ? NT - 1 : 1)];
  __shared__ int eCons[NT + 1];
  __shared__ float cring[256];
  __shared__ float redV[NT];
  __shared__ int redJ[NT];
  volatile int* vProg = eProg;
  volatile int* vCons = eCons;

  if (t < (NT > 1 ? NT - 1 : 1)) vProg[t] = -1;
  if (t < NT + 1) vCons[t] = 0;
  if (W == 0 && hasCarry) {
    cring[lane] = carryIn[b * N_ + lane];
    cring[lane + 64] = carryIn[b * N_ + lane + 64];
    cring[lane + 128] = carryIn[b * N_ + lane + 128];
  }
  __syncthreads();

  const float INF = finf();
  const float* CsW = Cs + (size_t)(b * NT + W) * SROWS_ * 256;

  float4 cc0 = ((const float4*)(CsW + (size_t)0 * 256))[lane];
  float4 cc1 = ((const float4*)(CsW + (size_t)1 * 256))[lane];
  float4 cc2 = ((const float4*)(CsW + (size_t)2 * 256))[lane];
  float4 cc3 = ((const float4*)(CsW + (size_t)3 * 256))[lane];
  float4 cc4 = ((const float4*)(CsW + (size_t)4 * 256))[lane];
  float4 cc5 = ((const float4*)(CsW + (size_t)5 * 256))[lane];
  float4 cc6 = ((const float4*)(CsW + (size_t)6 * 256))[lane];
  float4 cc7 = ((const float4*)(CsW + (size_t)7 * 256))[lane];

  float up0 = 0.f, up1 = 0.f, up2 = 0.f, up3 = 0.f;
  float dpp1 = INF, dpp2 = INF, lrPrev = INF;
  float fin0 = INF, fin1 = INF, fin2 = INF, fin3 = INF;
  const int tileG = chunk * NT + W;
  unsigned char* decL = dec + (size_t)(b * 16 + tileG) * SROWS_ * 64 + lane;
  const int jbase = tileG * 256 + lane * 4;

#define DPSTEP(KK, CCV)                                                        \
  do {                                                                         \
    const int s = sb + (KK);                                                   \
    const int i = s - lane;                                                    \
    float lval;                                                                \
    if (NT > 1 && W > 0) lval = eRing[(W - 1) * 64 + (s & 63)];                \
    else if (hasCarry) lval = cring[s & 255];                                  \
    else lval = INF;                                                           \
    const bool row0 = (i == 0);                                                \
    const float left = (lane == 0) ? lval : dpp1;                              \
    const float diag = (lane == 0) ? lrPrev : dpp2;                            \
    lrPrev = lval;                                                             \
    float m0 = fminf(up0, left);                                               \
    float bv0 = fminf(diag, m0); bv0 = row0 ? 0.f : bv0;                       \
    const float D0 = CCV.x + bv0;                                              \
    unsigned int pk = (diag <= m0) ? 0u : ((up0 <= left) ? 1u : 2u);           \
    float m1 = fminf(up1, D0);                                                 \
    float bv1 = fminf(up0, m1); bv1 = row0 ? 0.f : bv1;                        \
    const float D1 = CCV.y + bv1;                                              \
    pk |= ((up0 <= m1) ? 0u : ((up1 <= D0) ? 1u : 2u)) << 2;                   \
    float m2 = fminf(up2, D1);                                                 \
    float bv2 = fminf(up1, m2); bv2 = row0 ? 0.f : bv2;                        \
    const float D2 = CCV.z + bv2;                                              \
    pk |= ((up1 <= m2) ? 0u : ((up2 <= D1) ? 1u : 2u)) << 4;                   \
    float m3 = fminf(up3, D2);                                                 \
    float bv3 = fminf(up2, m3); bv3 = row0 ? 0.f : bv3;                        \
    const float D3 = CCV.w + bv3;                                              \
    pk |= ((up2 <= m3) ? 0u : ((up3 <= D2) ? 1u : 2u)) << 6;                   \
    if (s < SROWS_) decL[(size_t)s * 64] = (unsigned char)pk;                  \
    const bool lastrow = (i == N_ - 1);                                        \
    fin0 = lastrow ? D0 : fin0; fin1 = lastrow ? D1 : fin1;                    \
    fin2 = lastrow ? D2 : fin2; fin3 = lastrow ? D3 : fin3;                    \
    if (W == NT - 1 && lane == 63 && (unsigned)i < (unsigned)N_)               \
      carryOut[b * N_ + i] = D3;                                               \
    const float sh = wave_shr1(D3);                                            \
    dpp2 = dpp1; dpp1 = sh;                                                    \
    up0 = D0; up1 = D1; up2 = D2; up3 = D3;                                    \
    if (NT > 1 && W < NT - 1) {                                                \
      const int rp = s - 63;                                                   \
      if (lane == 63 && (unsigned)rp < (unsigned)N_) {                         \
        eRing[W * 64 + (rp & 63)] = D3;                                        \
        if ((rp & 7) == 7) {                                                   \
          asm volatile("" ::: "memory");                                       \
          __builtin_amdgcn_s_waitcnt(0xC07F);                                  \
          vProg[W] = rp;                                                       \
          while (vCons[W + 1] < rp - 55) {}                                    \
        }                                                                      \
      }                                                                        \
    }                                                                          \
    {                                                                          \
      const int srow = sb + (KK) + 8;                                          \
      const int srowc = (srow < SROWS_) ? srow : (SROWS_ - 1);                 \
      CCV = ((const float4*)(CsW + (size_t)srowc * 256))[lane];                \
    }                                                                          \
  } while (0)

  for (int sb = 0; sb < 1088; sb += 8) {
    asm volatile("" ::: "memory");  // block fence: pin refill loads in-block
    if (NT > 1 && W > 0) {
      if (sb < N_) {
        if (lane == 0) vCons[W] = sb;
        const int tgt = (sb + 7 < N_) ? (sb + 7) : (N_ - 1);
        while (vProg[W - 1] < tgt) {}
        asm volatile("" ::: "memory");
      }
    } else if (W == 0 && hasCarry) {
      if ((sb & 63) == 0 && sb >= 64) {
        const int r = sb + 128 + lane;
        if (r < N_) cring[r & 255] = carryIn[b * N_ + r];
      }
    }
    DPSTEP(0, cc0);
    DPSTEP(1, cc1);
    DPSTEP(2, cc2);
    DPSTEP(3, cc3);
    DPSTEP(4, cc4);
    DPSTEP(5, cc5);
    DPSTEP(6, cc6);
    DPSTEP(7, cc7);
  }
#undef DPSTEP

  float mv = fin0; int mj = jbase;
  if (fin1 < mv) { mv = fin1; mj = jbase + 1; }
  if (fin2 < mv) { mv = fin2; mj = jbase + 2; }
  if (fin3 < mv) { mv = fin3; mj = jbase + 3; }
#pragma unroll
  for (int off = 32; off > 0; off >>= 1) {
    const float ov = __shfl_down(mv, off);
    const int oj = __shfl_down(mj, off);
    if (ov < mv || (ov == mv && oj < mj)) { mv = ov; mj = oj; }
  }
  if (lane == 0) { redV[W] = mv; redJ[W] = mj; }
  __syncthreads();
  if (t == 0) {
#pragma unroll
    for (int w = 1; w < NT; ++w)
      if (redV[w] < mv) { mv = redV[w]; mj = redJ[w]; }
    partV[b * nch + chunk] = mv;
    partJ[b * nch + chunk] = mj;
  }
}

// ---------------------------------------------------------------------------
// Backtrack over skewed dec. Per super-step: lane l loads a 96-quad window of
// row i-l; decodes a run-of-2 exit table (tab[c] = stop cell + its code) so
// the serial walk costs ~1 LDS read per row; parallel y_t gather at the end.
// ---------------------------------------------------------------------------
__global__ __launch_bounds__(64) void backtrack_kernel(
    const unsigned char* __restrict__ dec, const float* __restrict__ partV,
    const int* __restrict__ partJ, int nch, const float* __restrict__ y_t,
    float* __restrict__ w_vs, float* __restrict__ cost_out) {
  const int b = blockIdx.x;
  const int lane = threadIdx.x;
  __shared__ unsigned char win[64][BTQ_ + 4];
  __shared__ unsigned short tab[64][BTQ_ * 4 + 2];
  __shared__ int st_i, st_j;
  __shared__ int jrow[65];
  const size_t TS = (size_t)SROWS_ * 64;
  const unsigned char* db = dec + (size_t)b * 16 * TS;
  const float* yt = y_t + b * M_;
  float* wv = w_vs + b * N_;

  if (lane == 0) {
    float bc = finf(); int bj = 0;
    for (int c = 0; c < nch; ++c) {
      const float v = partV[b * nch + c];
      const int j = partJ[b * nch + c];
      if (v < bc) { bc = v; bj = j; }
    }
    cost_out[b] = bc;
    st_i = N_ - 1;
    st_j = bj;
    wv[N_ - 1] = yt[bj];
  }
  for (;;) {
    __syncthreads();
    const int i = st_i, j = st_j;
    if (i <= 0) break;
    const int qj = j >> 2;
    int qlo = qj - (BTQ_ - 1);
    if (qlo < 0) qlo = 0;
    const int r = i - lane;
    if (r >= 1) {
      for (int k = 0; k < BTQ_; ++k) {
        const int q = qlo + k;
        win[lane][k] = db[(size_t)(q >> 6) * TS + (size_t)(r + (q & 63)) * 64 + (q & 63)];
      }
      unsigned short run = 0xFFFF;  // stuck sentinel (run extends past window)
      for (int k = 0; k < BTQ_; ++k) {
        const unsigned int byte = win[lane][k];
#pragma unroll
        for (int cs = 0; cs < 4; ++cs) {
          const unsigned int code = (byte >> (2 * cs)) & 3u;
          const int c = 4 * k + cs;
          const unsigned short v =
              (code != 2u) ? (unsigned short)((c << 2) | code) : run;
          tab[lane][c] = v;
          run = v;
        }
      }
    }
    __syncthreads();
    if (lane == 0) {
      const int base = qlo << 2;
      int rr = i, cj = j;
      while (rr >= 1 && (i - rr) < 64) {
        const int l = i - rr;
        const int c = cj - base;
        if (c < 0) break;  // window exhausted; restart super-step
        const unsigned short v = tab[l][c];
        if (v == 0xFFFF) { cj = base - 1; break; }  // 2-run exits window
        const int e = v >> 2;
        const int ce = v & 3;
        cj = base + e - (ce == 0 ? 1 : 0);
        --rr;
        jrow[i - rr] = cj;
      }
      st_i = rr;
      st_j = cj;
    }
    __syncthreads();
    const int cnt = i - st_i;
    if (lane < cnt) wv[i - 1 - lane] = yt[jrow[lane + 1]];
  }
}

// ---------------------------------------------------------------------------
extern "C" void kernel_launch(void* const* d_in, const int* in_sizes, int n_in,
                              void* d_out, int out_size, void* d_ws, size_t ws_size,
                              hipStream_t stream) {
  const float* x = (const float*)d_in[0];
  const float* y = (const float*)d_in[1];
  const float* x_t = (const float*)d_in[2];
  const float* y_t = (const float*)d_in[3];

  float* out_cost = (float*)d_out;      // [B_]
  float* out_wts = out_cost + B_;       // [B_][N_]
  float* out_wvs = out_wts + B_ * N_;   // [B_][N_]

  const size_t decBytes = (size_t)B_ * 16 * SROWS_ * 64;   // 17.8 MB (skewed)
  const size_t x2Bytes = (size_t)B_ * N_ * 4;
  const size_t carryBytes = (size_t)B_ * N_ * 4;
  const size_t partBytes = (size_t)B_ * 8 * 4;
  const size_t cs4 = (size_t)B_ * 4 * SROWS_ * 256 * 4;    // 71.2 MB
  const size_t need4 = cs4 + decBytes + x2Bytes + 2 * carryBytes + 2 * partBytes;

  const int NT = (ws_size >= need4) ? 4 : 2;
  const int NCH = 16 / NT;
  const size_t csBytes = (size_t)B_ * NT * SROWS_ * 256 * 4;

  char* ws = (char*)d_ws;
  float* Cs = (float*)ws;
  unsigned char* dec = (unsigned char*)(ws + csBytes);
  float* x2 = (float*)(ws + csBytes + decBytes);
  float* carryA = (float*)(ws + csBytes + decBytes + x2Bytes);
  float* carryB = carryA + B_ * N_;
  float* partV = carryB + B_ * N_;
  int* partJ = (int*)(partV + B_ * 8);

  prep_kernel<<<dim3((B_ * N_) / 256), 256, 0, stream>>>(x, x_t, x2, out_wts);

  float* cbuf[2] = {carryA, carryB};
  for (int c = 0; c < NCH; ++c) {
    const int chunkBase = c * NT * 256;
    gemm_kernel<<<dim3(NT, N_ / 128, B_), 256, 0, stream>>>(x, y, x2, Cs,
                                                            chunkBase, NT);
    const float* cin = cbuf[(c + 1) & 1];
    float* cout = cbuf[c & 1];
    if (NT == 4) {
      dtw_dp_systolic<4><<<dim3(B_), 256, 0, stream>>>(
          Cs, dec, cin, cout, partV, partJ, c, NCH, c > 0 ? 1 : 0);
    } else {
      dtw_dp_systolic<2><<<dim3(B_), 128, 0, stream>>>(
          Cs, dec, cin, cout, partV, partJ, c, NCH, c > 0 ? 1 : 0);
    }
  }

  backtrack_kernel<<<dim3(B_), 64, 0, stream>>>(dec, partV, partJ, NCH, y_t,
                                                out_wvs, out_cost);
}